// Round 11
// baseline (64.057 us; speedup 1.0000x reference)
//
#include <hip/hip_runtime.h>

// Go board features, fully fused: one block per board (256 threads, ~13KB LDS,
// 8 blocks/CU). Packed color|label LDS words; empty-row zero-fill issued before
// the label loop (HBM writeback overlaps label compute). Pooling = wave-per-
// group gather with a 2-deep software pipeline (next group's meta+first-row
// load issued before current group's reduce/stores) + packed group meta.

constexpr int BOARD = 19;
constexpr int NN = BOARD * BOARD;   // 361
constexpr int DD = 64;
constexpr int NT = 256;             // 4 waves
constexpr int NW = NT / 64;         // 4
constexpr int NQ = NN * (DD / 4);   // 5776 float4 per board

typedef float f4v __attribute__((ext_vector_type(4)));   // nt-store-compatible

// packed cell word: bits[11:10] = color+1 (0 empty, 1 black, 2 white),
// bits[9:0] = label (cell index < 1024). min() on words with equal color
// bits == min on labels; labels only ever decrease within a component.

__global__ __launch_bounds__(NT) void go_board(
    const int* __restrict__ stones,   // B*2*361, storage dtype detected at runtime
    const int* __restrict__ ko,       // B*2 int32
    const float* __restrict__ feat,   // B*361*64 f32
    float* __restrict__ o_feats,      // B*361*64
    float* __restrict__ o_libs,       // B*361
    float* __restrict__ o_legal,      // B*361
    float* __restrict__ o_scores)     // B*2
{
    const int b = blockIdx.x;
    const int tid = threadIdx.x;

    __shared__ int s_cl[NN];          // packed color|label
    __shared__ int s_libs[NN];
    __shared__ int s_cnt[NN];         // stones per root label
    __shared__ int s_start[NN];       // exclusive scan of s_cnt
    __shared__ int s_ptr[NN];         // fill cursor
    __shared__ int s_members[NN];     // cell indices grouped by label
    __shared__ int s_glist[NN];       // compacted list of group roots
    __shared__ int s_gm[NN];          // flat: (start | cnt<<16) per compact gid
    __shared__ int s_ng;              // number of groups
    __shared__ int s_sc[2];
    __shared__ int s_changed;
    __shared__ unsigned int s_orw;

    if (tid == 0) { s_orw = 0u; s_sc[0] = 0; s_sc[1] = 0; s_ng = 0; }
    __syncthreads();

    // ---- detect stones storage width (int32 0/1 vs packed bytes vs f32) ----
    {
        unsigned int acc = 0u;
        const unsigned int* w = (const unsigned int*)stones;
        for (int i = tid; i < 768; i += NT) acc |= w[i];
        for (int off = 32; off > 0; off >>= 1)
            acc |= (unsigned int)__shfl_xor((int)acc, off, 64);
        if ((tid & 63) == 0 && acc) atomicOr(&s_orw, acc);
    }
    __syncthreads();
    const unsigned int orw = s_orw;
    const int mode = (orw <= 1u) ? 0 : (((orw & 0xFEFEFEFEu) == 0u) ? 1 : 2);

    // ---- init packed color|label + counters ----
    for (int i = tid; i < NN; i += NT) {
        int blk, wht;
        const size_t base = (size_t)b * (2 * NN);
        if (mode == 0) {
            blk = stones[base + i] != 0;
            wht = stones[base + NN + i] != 0;
        } else if (mode == 1) {
            const unsigned char* s8 = (const unsigned char*)stones;
            blk = s8[base + i] != 0;
            wht = s8[base + NN + i] != 0;
        } else {
            const float* sf = (const float*)stones;
            blk = sf[base + i] != 0.0f;
            wht = sf[base + NN + i] != 0.0f;
        }
        const int cc = blk ? 1 : ((wht && !blk) ? 2 : 0);  // white = s1 & ~s0
        s_cl[i] = (cc << 10) | i;
        s_libs[i] = 0;
        s_cnt[i] = 0;
    }
    __syncthreads();

    const float* fbase = feat + (size_t)b * NN * DD;
    f4v* o4 = (f4v*)o_feats + (size_t)b * NQ;

    // ---- zero-fill empty output rows NOW: nt stores ack at L2 and write
    //      back to HBM while the label loop below runs ----
    {
        const f4v z = {0.f, 0.f, 0.f, 0.f};
        for (int p = tid; p < NQ; p += NT) {
            const int cell = p >> 4;
            if ((s_cl[cell] >> 10) == 0)
                __builtin_nontemporal_store(z, &o4[p]);
        }
    }

    // ---- min-label propagation: packed words, 2 sweeps per barrier round ----
    auto sweep = [&]() {
        for (int i = tid; i < NN; i += NT) {
            const int w = s_cl[i];
            if (w >> 10) {
                int m = w;
                const int r = i / BOARD;
                const int q = i - r * BOARD;
                if (r > 0)         { const int nw = s_cl[i - BOARD]; if (!((nw ^ w) >> 10)) m = min(m, nw); }
                if (r < BOARD - 1) { const int nw = s_cl[i + BOARD]; if (!((nw ^ w) >> 10)) m = min(m, nw); }
                if (q > 0)         { const int nw = s_cl[i - 1];     if (!((nw ^ w) >> 10)) m = min(m, nw); }
                if (q < BOARD - 1) { const int nw = s_cl[i + 1];     if (!((nw ^ w) >> 10)) m = min(m, nw); }
                m = min(m, s_cl[m & 1023]);   // pointer jump (same component)
                if (m < w) { s_cl[i] = m; s_changed = 1; }
            }
        }
    };
    for (int it = 0; it < 64; ++it) {
        __syncthreads();
        if (tid == 0) s_changed = 0;
        __syncthreads();
        sweep();
        sweep();                          // monotone -> no barrier needed between
        __syncthreads();
        if (!s_changed) break;
    }

    // ---- liberties (dedup in DIRS order), stone counts, group roots ----
    for (int i = tid; i < NN; i += NT) {
        const int w = s_cl[i];
        if ((w >> 10) == 0) {             // empty: scatter liberties
            const int r = i / BOARD;
            const int q = i - r * BOARD;
            int l0 = NN, l1 = NN, l2 = NN, l3 = NN;
            if (r > 0)         { const int nw = s_cl[i - BOARD]; if (nw >> 10) l0 = nw & 1023; }
            if (r < BOARD - 1) { const int nw = s_cl[i + BOARD]; if (nw >> 10) l1 = nw & 1023; }
            if (q > 0)         { const int nw = s_cl[i - 1];     if (nw >> 10) l2 = nw & 1023; }
            if (q < BOARD - 1) { const int nw = s_cl[i + 1];     if (nw >> 10) l3 = nw & 1023; }
            if (l0 < NN)                                     atomicAdd(&s_libs[l0], 1);
            if (l1 < NN && l1 != l0)                         atomicAdd(&s_libs[l1], 1);
            if (l2 < NN && l2 != l0 && l2 != l1)             atomicAdd(&s_libs[l2], 1);
            if (l3 < NN && l3 != l0 && l3 != l1 && l3 != l2) atomicAdd(&s_libs[l3], 1);
        } else {
            atomicAdd(&s_sc[(w >> 10) - 1], 1);
            const int lab = w & 1023;
            atomicAdd(&s_cnt[lab], 1);
            if (lab == i) {               // group root -> compact list
                const int gi = atomicAdd(&s_ng, 1);
                s_glist[gi] = i;
            }
        }
    }
    __syncthreads();

    // ---- exclusive scan of s_cnt (wave 0 only; 6 chunks of 64) ----
    if (tid < 64) {
        int carry = 0;
        for (int c = 0; c < 6; ++c) {
            const int i = c * 64 + tid;
            const int v = (i < NN) ? s_cnt[i] : 0;
            int x = v;
            for (int off = 1; off < 64; off <<= 1) {
                const int y = __shfl_up(x, off, 64);
                if (tid >= off) x += y;
            }
            if (i < NN) { s_start[i] = carry + x - v; s_ptr[i] = carry + x - v; }
            carry += __shfl(x, 63, 64);
        }
    }
    __syncthreads();

    // ---- fill member lists, pack group meta, small outputs ----
    const int ng = s_ng;
    const int kr = ko[2 * b];
    const int kc = ko[2 * b + 1];
    for (int i = tid; i < NN; i += NT) {
        const int w = s_cl[i];
        if (w >> 10) {
            const int pos = atomicAdd(&s_ptr[w & 1023], 1);
            s_members[pos] = i;
        }
        if (i < ng) {
            const int root = s_glist[i];
            s_gm[i] = s_start[root] | (s_cnt[root] << 16);
        }
        __builtin_nontemporal_store((float)s_libs[i], &o_libs[(size_t)b * NN + i]);
        bool legal = ((w >> 10) == 0);
        if (kr >= 0) {
            const int krr = min(max(kr, 0), BOARD - 1);
            const int kcc = min(max(kc, 0), BOARD - 1);
            if (i == krr * BOARD + kcc) legal = false;
        }
        __builtin_nontemporal_store(legal ? 1.0f : 0.0f, &o_legal[(size_t)b * NN + i]);
    }
    if (tid == 0) {
        o_scores[(size_t)b * 2 + 0] = (float)s_sc[0];
        o_scores[(size_t)b * 2 + 1] = (float)s_sc[1];
    }
    __syncthreads();

    // ---- pooling: wave-per-group, 2-deep software pipeline ----
    // lane = mi*16 + q. While group g is reduced/stored, group g+NW's meta,
    // member index and first row-load are already in flight (no dependence on
    // g's compute), hiding the ~900cy HBM latency behind compute+stores.
    const float4* f4 = (const float4*)fbase;
    const int wave = tid >> 6;
    const int lane = tid & 63;
    const int mi = lane >> 4;
    const int q  = lane & 15;

    int g = wave;
    bool ok = g < ng;
    int meta = ok ? s_gm[g] : 0;
    int s0 = meta & 0xFFFF, c0 = meta >> 16;
    int m0 = (ok && mi < c0) ? s_members[s0 + mi] : -1;
    float4 v0 = make_float4(0.f, 0.f, 0.f, 0.f);
    if (m0 >= 0) v0 = f4[m0 * 16 + q];

    while (ok) {
        // issue next group's chain before touching the current one
        const int g1 = g + NW;
        const bool ok1 = g1 < ng;
        const int meta1 = ok1 ? s_gm[g1] : 0;
        const int s1 = meta1 & 0xFFFF, c1 = meta1 >> 16;
        const int m1 = (ok1 && mi < c1) ? s_members[s1 + mi] : -1;
        float4 v1 = make_float4(0.f, 0.f, 0.f, 0.f);
        if (m1 >= 0) v1 = f4[m1 * 16 + q];

        // finish current group
        float4 acc = v0;                   // zero for inactive lanes
        for (int k = mi + 4; k < c0; k += 4) {   // rare tail (cnt > 4)
            const float4 t = f4[s_members[s0 + k] * 16 + q];
            acc.x += t.x; acc.y += t.y; acc.z += t.z; acc.w += t.w;
        }
        if (c0 > 1) {   // wave-uniform; singleton groups skip the shfl reduce
            acc.x += __shfl_xor(acc.x, 16); acc.y += __shfl_xor(acc.y, 16);
            acc.z += __shfl_xor(acc.z, 16); acc.w += __shfl_xor(acc.w, 16);
            acc.x += __shfl_xor(acc.x, 32); acc.y += __shfl_xor(acc.y, 32);
            acc.z += __shfl_xor(acc.z, 32); acc.w += __shfl_xor(acc.w, 32);
        }
        const f4v av = {acc.x, acc.y, acc.z, acc.w};
        if (m0 >= 0)
            __builtin_nontemporal_store(av, &o4[m0 * 16 + q]);
        for (int k = mi + 4; k < c0; k += 4)
            __builtin_nontemporal_store(av, &o4[s_members[s0 + k] * 16 + q]);

        // rotate pipeline registers
        g = g1; ok = ok1; s0 = s1; c0 = c1; m0 = m1; v0 = v1;
    }
}

extern "C" void kernel_launch(void* const* d_in, const int* in_sizes, int n_in,
                              void* d_out, int out_size, void* d_ws, size_t ws_size,
                              hipStream_t stream) {
    // setup_inputs order: stones, ko_points, current_player, features
    const int* stones = (const int*)d_in[0];
    const int* ko     = (const int*)d_in[1];
    const float* feat = (const float*)d_in[3];
    float* out        = (float*)d_out;

    const int B = in_sizes[2];   // current_player has B elements

    float* o_feats  = out;
    float* o_libs   = o_feats + (size_t)B * NN * DD;
    float* o_legal  = o_libs  + (size_t)B * NN;
    float* o_scores = o_legal + (size_t)B * NN;

    go_board<<<B, NT, 0, stream>>>(stones, ko, feat,
                                   o_feats, o_libs, o_legal, o_scores);
}

// Round 12
// 63.540 us; speedup vs baseline: 1.0081x; 1.0081x over previous
//
#include <hip/hip_runtime.h>

// Go board features, fully fused: one block per board (256 threads, ~13KB LDS,
// 8 blocks/CU). Packed color|label LDS words; empty-row zero-fill issued before
// the label loop (HBM writeback overlaps label compute). NO feature prefetch
// (round-9 lesson: stone-row working set is 4x the per-XCD L2 -> prefetch
// doubles HBM fetch). Pooling = wave-per-group gather + shfl reduce + nt stores.
// Round-12 = round-10 revert (best measured); r5/r9/r11 latency levers all
// neutral-to-negative -> structure is at its scattered-256B-granule BW limit.

constexpr int BOARD = 19;
constexpr int NN = BOARD * BOARD;   // 361
constexpr int DD = 64;
constexpr int NT = 256;             // 4 waves
constexpr int NW = NT / 64;         // 4
constexpr int NQ = NN * (DD / 4);   // 5776 float4 per board

typedef float f4v __attribute__((ext_vector_type(4)));   // nt-store-compatible

// packed cell word: bits[11:10] = color+1 (0 empty, 1 black, 2 white),
// bits[9:0] = label (cell index < 1024). min() on words with equal color
// bits == min on labels; labels only ever decrease within a component.

__global__ __launch_bounds__(NT) void go_board(
    const int* __restrict__ stones,   // B*2*361, storage dtype detected at runtime
    const int* __restrict__ ko,       // B*2 int32
    const float* __restrict__ feat,   // B*361*64 f32
    float* __restrict__ o_feats,      // B*361*64
    float* __restrict__ o_libs,       // B*361
    float* __restrict__ o_legal,      // B*361
    float* __restrict__ o_scores)     // B*2
{
    const int b = blockIdx.x;
    const int tid = threadIdx.x;

    __shared__ int s_cl[NN];          // packed color|label
    __shared__ int s_libs[NN];
    __shared__ int s_cnt[NN];         // stones per root label
    __shared__ int s_start[NN];       // exclusive scan of s_cnt
    __shared__ int s_ptr[NN];         // fill cursor
    __shared__ int s_members[NN];     // cell indices grouped by label
    __shared__ int s_glist[NN];       // compacted list of group roots
    __shared__ int s_gs[NN];          // flat: start per compact group id
    __shared__ int s_gc[NN];          // flat: count per compact group id
    __shared__ int s_ng;              // number of groups
    __shared__ int s_sc[2];
    __shared__ int s_changed;
    __shared__ unsigned int s_orw;

    if (tid == 0) { s_orw = 0u; s_sc[0] = 0; s_sc[1] = 0; s_ng = 0; }
    __syncthreads();

    // ---- detect stones storage width (int32 0/1 vs packed bytes vs f32) ----
    {
        unsigned int acc = 0u;
        const unsigned int* w = (const unsigned int*)stones;
        for (int i = tid; i < 768; i += NT) acc |= w[i];
        for (int off = 32; off > 0; off >>= 1)
            acc |= (unsigned int)__shfl_xor((int)acc, off, 64);
        if ((tid & 63) == 0 && acc) atomicOr(&s_orw, acc);
    }
    __syncthreads();
    const unsigned int orw = s_orw;
    const int mode = (orw <= 1u) ? 0 : (((orw & 0xFEFEFEFEu) == 0u) ? 1 : 2);

    // ---- init packed color|label + counters ----
    for (int i = tid; i < NN; i += NT) {
        int blk, wht;
        const size_t base = (size_t)b * (2 * NN);
        if (mode == 0) {
            blk = stones[base + i] != 0;
            wht = stones[base + NN + i] != 0;
        } else if (mode == 1) {
            const unsigned char* s8 = (const unsigned char*)stones;
            blk = s8[base + i] != 0;
            wht = s8[base + NN + i] != 0;
        } else {
            const float* sf = (const float*)stones;
            blk = sf[base + i] != 0.0f;
            wht = sf[base + NN + i] != 0.0f;
        }
        const int cc = blk ? 1 : ((wht && !blk) ? 2 : 0);  // white = s1 & ~s0
        s_cl[i] = (cc << 10) | i;
        s_libs[i] = 0;
        s_cnt[i] = 0;
    }
    __syncthreads();

    const float* fbase = feat + (size_t)b * NN * DD;
    f4v* o4 = (f4v*)o_feats + (size_t)b * NQ;

    // ---- zero-fill empty output rows NOW: nt stores ack at L2 and write
    //      back to HBM while the label loop below runs ----
    {
        const f4v z = {0.f, 0.f, 0.f, 0.f};
        for (int p = tid; p < NQ; p += NT) {
            const int cell = p >> 4;
            if ((s_cl[cell] >> 10) == 0)
                __builtin_nontemporal_store(z, &o4[p]);
        }
    }

    // ---- min-label propagation: packed words, 2 sweeps per barrier round ----
    auto sweep = [&]() {
        for (int i = tid; i < NN; i += NT) {
            const int w = s_cl[i];
            if (w >> 10) {
                int m = w;
                const int r = i / BOARD;
                const int q = i - r * BOARD;
                if (r > 0)         { const int nw = s_cl[i - BOARD]; if (!((nw ^ w) >> 10)) m = min(m, nw); }
                if (r < BOARD - 1) { const int nw = s_cl[i + BOARD]; if (!((nw ^ w) >> 10)) m = min(m, nw); }
                if (q > 0)         { const int nw = s_cl[i - 1];     if (!((nw ^ w) >> 10)) m = min(m, nw); }
                if (q < BOARD - 1) { const int nw = s_cl[i + 1];     if (!((nw ^ w) >> 10)) m = min(m, nw); }
                m = min(m, s_cl[m & 1023]);   // pointer jump (same component)
                if (m < w) { s_cl[i] = m; s_changed = 1; }
            }
        }
    };
    for (int it = 0; it < 64; ++it) {
        __syncthreads();
        if (tid == 0) s_changed = 0;
        __syncthreads();
        sweep();
        sweep();                          // monotone -> no barrier needed between
        __syncthreads();
        if (!s_changed) break;
    }

    // ---- liberties (dedup in DIRS order), stone counts, group roots ----
    for (int i = tid; i < NN; i += NT) {
        const int w = s_cl[i];
        if ((w >> 10) == 0) {             // empty: scatter liberties
            const int r = i / BOARD;
            const int q = i - r * BOARD;
            int l0 = NN, l1 = NN, l2 = NN, l3 = NN;
            if (r > 0)         { const int nw = s_cl[i - BOARD]; if (nw >> 10) l0 = nw & 1023; }
            if (r < BOARD - 1) { const int nw = s_cl[i + BOARD]; if (nw >> 10) l1 = nw & 1023; }
            if (q > 0)         { const int nw = s_cl[i - 1];     if (nw >> 10) l2 = nw & 1023; }
            if (q < BOARD - 1) { const int nw = s_cl[i + 1];     if (nw >> 10) l3 = nw & 1023; }
            if (l0 < NN)                                     atomicAdd(&s_libs[l0], 1);
            if (l1 < NN && l1 != l0)                         atomicAdd(&s_libs[l1], 1);
            if (l2 < NN && l2 != l0 && l2 != l1)             atomicAdd(&s_libs[l2], 1);
            if (l3 < NN && l3 != l0 && l3 != l1 && l3 != l2) atomicAdd(&s_libs[l3], 1);
        } else {
            atomicAdd(&s_sc[(w >> 10) - 1], 1);
            const int lab = w & 1023;
            atomicAdd(&s_cnt[lab], 1);
            if (lab == i) {               // group root -> compact list
                const int gi = atomicAdd(&s_ng, 1);
                s_glist[gi] = i;
            }
        }
    }
    __syncthreads();

    // ---- exclusive scan of s_cnt (wave 0 only; 6 chunks of 64) ----
    if (tid < 64) {
        int carry = 0;
        for (int c = 0; c < 6; ++c) {
            const int i = c * 64 + tid;
            const int v = (i < NN) ? s_cnt[i] : 0;
            int x = v;
            for (int off = 1; off < 64; off <<= 1) {
                const int y = __shfl_up(x, off, 64);
                if (tid >= off) x += y;
            }
            if (i < NN) { s_start[i] = carry + x - v; s_ptr[i] = carry + x - v; }
            carry += __shfl(x, 63, 64);
        }
    }
    __syncthreads();

    // ---- fill member lists, flatten group meta, small outputs ----
    const int ng = s_ng;
    const int kr = ko[2 * b];
    const int kc = ko[2 * b + 1];
    for (int i = tid; i < NN; i += NT) {
        const int w = s_cl[i];
        if (w >> 10) {
            const int pos = atomicAdd(&s_ptr[w & 1023], 1);
            s_members[pos] = i;
        }
        if (i < ng) {
            const int root = s_glist[i];
            s_gs[i] = s_start[root];
            s_gc[i] = s_cnt[root];
        }
        __builtin_nontemporal_store((float)s_libs[i], &o_libs[(size_t)b * NN + i]);
        bool legal = ((w >> 10) == 0);
        if (kr >= 0) {
            const int krr = min(max(kr, 0), BOARD - 1);
            const int kcc = min(max(kc, 0), BOARD - 1);
            if (i == krr * BOARD + kcc) legal = false;
        }
        __builtin_nontemporal_store(legal ? 1.0f : 0.0f, &o_legal[(size_t)b * NN + i]);
    }
    if (tid == 0) {
        o_scores[(size_t)b * 2 + 0] = (float)s_sc[0];
        o_scores[(size_t)b * 2 + 1] = (float)s_sc[1];
    }
    __syncthreads();

    // ---- pooling: one wave per group; sum once, broadcast to members ----
    // lane = mi*16 + q: 4 member-lanes x 16 quads; each load/store instruction
    // covers 4 contiguous 256B rows. shfl_xor(16,32) reduces over mi.
    const float4* f4 = (const float4*)fbase;
    const int wave = tid >> 6;
    const int lane = tid & 63;
    const int mi = lane >> 4;
    const int q  = lane & 15;
    for (int g = wave; g < ng; g += NW) {
        const int s = s_gs[g];
        const int cnt = s_gc[g];
        float4 acc = make_float4(0.f, 0.f, 0.f, 0.f);
        for (int k = mi; k < cnt; k += 4) {
            const float4 v = f4[s_members[s + k] * 16 + q];
            acc.x += v.x; acc.y += v.y; acc.z += v.z; acc.w += v.w;
        }
        if (cnt > 1) {   // wave-uniform; singleton groups skip the shfl reduce
            acc.x += __shfl_xor(acc.x, 16); acc.y += __shfl_xor(acc.y, 16);
            acc.z += __shfl_xor(acc.z, 16); acc.w += __shfl_xor(acc.w, 16);
            acc.x += __shfl_xor(acc.x, 32); acc.y += __shfl_xor(acc.y, 32);
            acc.z += __shfl_xor(acc.z, 32); acc.w += __shfl_xor(acc.w, 32);
        }
        // broadcast-write the group sum to every member row (streaming, nt)
        const f4v av = {acc.x, acc.y, acc.z, acc.w};
        for (int k = mi; k < cnt; k += 4) {
            __builtin_nontemporal_store(av, &o4[s_members[s + k] * 16 + q]);
        }
    }
}

extern "C" void kernel_launch(void* const* d_in, const int* in_sizes, int n_in,
                              void* d_out, int out_size, void* d_ws, size_t ws_size,
                              hipStream_t stream) {
    // setup_inputs order: stones, ko_points, current_player, features
    const int* stones = (const int*)d_in[0];
    const int* ko     = (const int*)d_in[1];
    const float* feat = (const float*)d_in[3];
    float* out        = (float*)d_out;

    const int B = in_sizes[2];   // current_player has B elements

    float* o_feats  = out;
    float* o_libs   = o_feats + (size_t)B * NN * DD;
    float* o_legal  = o_libs  + (size_t)B * NN;
    float* o_scores = o_legal + (size_t)B * NN;

    go_board<<<B, NT, 0, stream>>>(stones, ko, feat,
                                   o_feats, o_libs, o_legal, o_scores);
}